// Round 11
// baseline (486.471 us; speedup 1.0000x reference)
//
#include <hip/hip_runtime.h>
#include <math.h>

#define G     128
#define NPER  512
#define NTOT  65536
#define E_TOT 1048576
#define EPG   8192
#define INC   100
#define HID   128
#define KP1   410
#define KP2   328
#define KP3   263

// monotone float<->uint encoding for atomicMax over signed floats
__device__ __forceinline__ unsigned encf(float x) {
    unsigned u = __float_as_uint(x);
    return (u & 0x80000000u) ? ~u : (u | 0x80000000u);
}
__device__ __forceinline__ float decf(unsigned e) {
    return (e & 0x80000000u) ? __uint_as_float(e ^ 0x80000000u)
                             : __uint_as_float(~e);
}

// ---------------------------------------------------------------------------
// init: identity cmap, zero bnpart(3 layers) + rmax(enc 0 == -inf) + rsum
// ---------------------------------------------------------------------------
__global__ void init_kernel(short* __restrict__ cmap, float* __restrict__ bnpart,
                            unsigned* __restrict__ rmax, float* __restrict__ rsum) {
    int t = blockIdx.x * 256 + threadIdx.x;
    if (t < NTOT) cmap[t] = (short)(t & (NPER - 1));
    if (t < 3 * G * 256) bnpart[t] = 0.f;
    if (t < 3 * G * 128) { rmax[t] = 0u; rsum[t] = 0.f; }
}

// ---------------------------------------------------------------------------
// csr_build0: layer-1 CSR (identity mapping, all edges valid).
// ---------------------------------------------------------------------------
__global__ __launch_bounds__(512, 2) void csr_build0(
    const int* __restrict__ src, const int* __restrict__ dst,
    unsigned short* __restrict__ csr_g, int* __restrict__ rowptr_g)
{
    __shared__ int cnt_s[NPER];
    __shared__ int rowptr_s[NPER + 1];
    __shared__ int wo_s[NPER];
    __shared__ int chunksum_s[9];

    const int g = blockIdx.x, tid = threadIdx.x, lane = tid & 63, wv = tid >> 6;
    const int ebase = g * EPG, obase = g * NPER;

    cnt_s[tid] = 0;
    __syncthreads();
    for (int e = tid; e < EPG; e += 512)
        atomicAdd(&cnt_s[dst[ebase + e] - obase], 1);
    __syncthreads();

    int v = cnt_s[tid], x = v;
#pragma unroll
    for (int d = 1; d < 64; d <<= 1) {
        int y = __shfl_up(x, d);
        if (lane >= d) x += y;
    }
    if (lane == 63) chunksum_s[wv] = x;
    __syncthreads();
    if (tid == 0) {
        int acc = 0;
#pragma unroll
        for (int k = 0; k < 8; ++k) { int t = chunksum_s[k]; chunksum_s[k] = acc; acc += t; }
    }
    __syncthreads();
    int excl = x - v + chunksum_s[wv];
    rowptr_s[tid] = excl; wo_s[tid] = excl;
    if (tid == 511) rowptr_s[512] = excl + v;
    __syncthreads();

    for (int i = tid; i <= NPER; i += 512) rowptr_g[g * 513 + i] = rowptr_s[i];
    for (int e = tid; e < EPG; e += 512) {
        int sl = src[ebase + e] - obase, dl = dst[ebase + e] - obase;
        int pos = atomicAdd(&wo_s[dl], 1);
        csr_g[g * EPG + pos] = (unsigned short)sl;
    }
}

// ---------------------------------------------------------------------------
// gemm_pre: out = relu(A[M x 100] @ W[100 x 128] + b).
// ---------------------------------------------------------------------------
__global__ __launch_bounds__(256, 2) void gemm_pre(
    const float* __restrict__ A, const float* __restrict__ W,
    const float* __restrict__ bias, float* __restrict__ out, int M)
{
    constexpr int K = INC, KC = 32;
    __shared__ float Ws[KC][128];
    __shared__ float As[KC][132];
    const int tid  = threadIdx.x;
    const int row0 = blockIdx.x * 128;
    const int r0 = (tid >> 4) * 8;
    const int c0 = (tid & 15) * 8;

    float acc[8][8];
#pragma unroll
    for (int i = 0; i < 8; ++i)
#pragma unroll
        for (int j = 0; j < 8; ++j) acc[i][j] = 0.f;

    for (int k0 = 0; k0 < K; k0 += KC) {
        const int kc  = (K - k0 < KC) ? (K - k0) : KC;
        const int nf4 = kc >> 2;

        for (int i = tid; i < kc * 32; i += 256) {
            int kk = i >> 5, c4 = i & 31;
            *((float4*)&Ws[kk][0] + c4) =
                *((const float4*)(W + (size_t)(k0 + kk) * 128) + c4);
        }
        for (int i = tid; i < nf4 * 128; i += 256) {
            int row = i / nf4, f4 = i - row * nf4;
            float4 v = *(const float4*)(A + (size_t)(row0 + row) * K + k0 + f4 * 4);
            As[f4 * 4 + 0][row] = v.x;
            As[f4 * 4 + 1][row] = v.y;
            As[f4 * 4 + 2][row] = v.z;
            As[f4 * 4 + 3][row] = v.w;
        }
        __syncthreads();

#pragma unroll 4
        for (int kk = 0; kk < kc; ++kk) {
            float4 b0 = *(const float4*)&Ws[kk][c0];
            float4 b1 = *(const float4*)&Ws[kk][c0 + 4];
            float4 a0 = *(const float4*)&As[kk][r0];
            float4 a1 = *(const float4*)&As[kk][r0 + 4];
            float a[8] = {a0.x, a0.y, a0.z, a0.w, a1.x, a1.y, a1.z, a1.w};
            float b[8] = {b0.x, b0.y, b0.z, b0.w, b1.x, b1.y, b1.z, b1.w};
#pragma unroll
            for (int i = 0; i < 8; ++i)
#pragma unroll
                for (int j = 0; j < 8; ++j)
                    acc[i][j] += a[i] * b[j];
        }
        __syncthreads();
    }

#pragma unroll
    for (int i = 0; i < 8; ++i) {
        int row = row0 + r0 + i;
        float o[8];
#pragma unroll
        for (int j = 0; j < 8; ++j)
            o[j] = fmaxf(acc[i][j] + bias[c0 + j], 0.f);
        float* po = out + (size_t)row * 128 + c0;
        *(float4*)po       = make_float4(o[0], o[1], o[2], o[3]);
        *(float4*)(po + 4) = make_float4(o[4], o[5], o[6], o[7]);
    }
}

// ---------------------------------------------------------------------------
// gemm128<NCUR>: out[row] = dinv_row * (A[row] @ W), double-buffered LDS.
// ---------------------------------------------------------------------------
template<int NCUR>
__global__ __launch_bounds__(256, 2) void gemm128(
    const float* __restrict__ A, const float* __restrict__ W,
    const int* __restrict__ rowptr_g, float* __restrict__ out)
{
    constexpr int KC = 32;
    __shared__ float Ws[2][KC][128];
    __shared__ float As[2][KC][132];
    __shared__ float dinv_ls[128];
    const int tid  = threadIdx.x;
    const int row0 = blockIdx.x * 128;
    const int r0 = (tid >> 4) * 8;
    const int c0 = (tid & 15) * 8;

    if (tid < 128) {
        int row = row0 + tid;
        int gg = row / NCUR, ll = row - gg * NCUR;
        const int* rp = rowptr_g + gg * 513 + ll;
        dinv_ls[tid] = rsqrtf((float)(rp[1] - rp[0] + 1));
    }

    const float4* W4 = (const float4*)W;

#pragma unroll
    for (int j = 0; j < 4; ++j) {
        int i = tid + j * 256;
        int kk = i >> 5, c4 = i & 31;
        *((float4*)&Ws[0][kk][0] + c4) = W4[kk * 32 + c4];
    }
#pragma unroll
    for (int j = 0; j < 4; ++j) {
        int i = tid + j * 256;
        int row = i >> 3, f4 = i & 7;
        float4 v = *(const float4*)(A + (size_t)(row0 + row) * 128 + f4 * 4);
        As[0][f4 * 4 + 0][row] = v.x;
        As[0][f4 * 4 + 1][row] = v.y;
        As[0][f4 * 4 + 2][row] = v.z;
        As[0][f4 * 4 + 3][row] = v.w;
    }
    __syncthreads();

    float acc[8][8];
#pragma unroll
    for (int i = 0; i < 8; ++i)
#pragma unroll
        for (int j = 0; j < 8; ++j) acc[i][j] = 0.f;

    int p = 0;
    for (int k0 = 0; k0 < 128; k0 += KC) {
        const int kn = k0 + KC;
        const bool has = kn < 128;

        float4 wreg[4], areg[4];
        if (has) {
#pragma unroll
            for (int j = 0; j < 4; ++j) {
                int i = tid + j * 256;
                int kk = i >> 5, c4 = i & 31;
                wreg[j] = W4[(kn + kk) * 32 + c4];
            }
#pragma unroll
            for (int j = 0; j < 4; ++j) {
                int i = tid + j * 256;
                int row = i >> 3, f4 = i & 7;
                areg[j] = *(const float4*)(A + (size_t)(row0 + row) * 128 + kn + f4 * 4);
            }
        }

#pragma unroll 4
        for (int kk = 0; kk < KC; ++kk) {
            float4 b0 = *(const float4*)&Ws[p][kk][c0];
            float4 b1 = *(const float4*)&Ws[p][kk][c0 + 4];
            float4 a0 = *(const float4*)&As[p][kk][r0];
            float4 a1 = *(const float4*)&As[p][kk][r0 + 4];
            float a[8] = {a0.x, a0.y, a0.z, a0.w, a1.x, a1.y, a1.z, a1.w};
            float b[8] = {b0.x, b0.y, b0.z, b0.w, b1.x, b1.y, b1.z, b1.w};
#pragma unroll
            for (int i = 0; i < 8; ++i)
#pragma unroll
                for (int j = 0; j < 8; ++j)
                    acc[i][j] += a[i] * b[j];
        }

        if (has) {
            int q = p ^ 1;
#pragma unroll
            for (int j = 0; j < 4; ++j) {
                int i = tid + j * 256;
                int kk = i >> 5, c4 = i & 31;
                *((float4*)&Ws[q][kk][0] + c4) = wreg[j];
            }
#pragma unroll
            for (int j = 0; j < 4; ++j) {
                int i = tid + j * 256;
                int row = i >> 3, f4 = i & 7;
                float4 v = areg[j];
                As[q][f4 * 4 + 0][row] = v.x;
                As[q][f4 * 4 + 1][row] = v.y;
                As[q][f4 * 4 + 2][row] = v.z;
                As[q][f4 * 4 + 3][row] = v.w;
            }
        }
        __syncthreads();
        p ^= 1;
    }

#pragma unroll
    for (int i = 0; i < 8; ++i) {
        int row = row0 + r0 + i;
        float dv = dinv_ls[r0 + i];
        float o[8];
#pragma unroll
        for (int j = 0; j < 8; ++j) o[j] = acc[i][j] * dv;
        float* po = out + (size_t)row * 128 + c0;
        *(float4*)po       = make_float4(o[0], o[1], o[2], o[3]);
        *(float4*)(po + 4) = make_float4(o[4], o[5], o[6], o[7]);
    }
}

// ---------------------------------------------------------------------------
// gather v5: input xs PRE-SCALED. grid (G,16), 256 thr, dual-row ILP.
// ---------------------------------------------------------------------------
template<int NCUR>
__global__ __launch_bounds__(256, 8) void gather_kernel(
    const float* __restrict__ xs, const unsigned short* __restrict__ csr_g,
    const int* __restrict__ rowptr_g, const float* __restrict__ bvec,
    float* __restrict__ out, float* __restrict__ bnpart)
{
    constexpr int CHUNK = (NCUR + 15) / 16;
    constexpr int CSRCAP = 1536;
    __shared__ int   rowptr_s[CHUNK + 1];
    __shared__ unsigned short csr_s[CSRCAP];
    __shared__ float red_s[512];

    const int g = blockIdx.x, s = blockIdx.y;
    const int tid = threadIdx.x, lane = tid & 63, w = tid >> 6;
    const int nbase = g * NCUR;
    const int d0 = s * CHUNK;
    const int d1 = (d0 + CHUNK < NCUR) ? d0 + CHUNK : NCUR;
    const int len = d1 - d0;

    const int* rp = rowptr_g + g * 513 + d0;
    for (int i = tid; i <= len; i += 256) rowptr_s[i] = rp[i];
    __syncthreads();

    const int base = rowptr_s[0];
    int nume = rowptr_s[len] - base;
    if (nume > CSRCAP) nume = CSRCAP;
    const unsigned short* cg = csr_g + g * EPG + base;
    for (int i = tid; i < nume; i += 256) csr_s[i] = cg[i];
    __syncthreads();

    const float2* x2g = (const float2*)xs + (size_t)nbase * 64 + lane;
    float2* o2p = (float2*)out;
    const float2 b2 = ((const float2*)bvec)[lane];
    float2 sum = make_float2(0.f, 0.f), sq = make_float2(0.f, 0.f);

    for (int da = d0 + w; da < d1; da += 8) {
        const int db = da + 4;
        const bool hb = db < d1;
        const int ra = da - d0, rb = db - d0;
        const int ia = rowptr_s[ra] - base;
        const int na = rowptr_s[ra + 1] - rowptr_s[ra];
        const int ib = hb ? rowptr_s[rb] - base : 0;
        const int nbl = hb ? rowptr_s[rb + 1] - rowptr_s[rb] : 0;
        const float dva = rsqrtf((float)(na + 1));
        const float dvb = rsqrtf((float)(nbl + 1));

        float2 accA = x2g[(size_t)da * 64];
        float2 accB = make_float2(0.f, 0.f);
        if (hb) accB = x2g[(size_t)db * 64];

        const int nmin = na < nbl ? na : nbl;
#pragma unroll 2
        for (int t = 0; t < nmin; ++t) {
            int sa = csr_s[ia + t], sb = csr_s[ib + t];
            float2 va = x2g[(size_t)sa * 64];
            float2 vb = x2g[(size_t)sb * 64];
            accA.x += va.x; accA.y += va.y;
            accB.x += vb.x; accB.y += vb.y;
        }
#pragma unroll 4
        for (int t = nmin; t < na; ++t) {
            float2 va = x2g[(size_t)csr_s[ia + t] * 64];
            accA.x += va.x; accA.y += va.y;
        }
#pragma unroll 4
        for (int t = nmin; t < nbl; ++t) {
            float2 vb = x2g[(size_t)csr_s[ib + t] * 64];
            accB.x += vb.x; accB.y += vb.y;
        }

        float2 oA = make_float2(b2.x + dva * accA.x, b2.y + dva * accA.y);
        o2p[(size_t)(nbase + da) * 64 + lane] = oA;
        sum.x += oA.x; sum.y += oA.y;
        sq.x  += oA.x * oA.x; sq.y += oA.y * oA.y;
        if (hb) {
            float2 oB = make_float2(b2.x + dvb * accB.x, b2.y + dvb * accB.y);
            o2p[(size_t)(nbase + db) * 64 + lane] = oB;
            sum.x += oB.x; sum.y += oB.y;
            sq.x  += oB.x * oB.x; sq.y += oB.y * oB.y;
        }
    }

    float2* red2 = (float2*)red_s;
    red2[tid] = sum; __syncthreads();
    if (tid < 64) {
        float2 a = red2[tid], b_ = red2[tid + 64],
               c = red2[tid + 128], d_ = red2[tid + 192];
        atomicAdd(&bnpart[g * 256 + 2 * tid],     a.x + b_.x + c.x + d_.x);
        atomicAdd(&bnpart[g * 256 + 2 * tid + 1], a.y + b_.y + c.y + d_.y);
    }
    __syncthreads();
    red2[tid] = sq; __syncthreads();
    if (tid < 64) {
        float2 a = red2[tid], b_ = red2[tid + 64],
               c = red2[tid + 128], d_ = red2[tid + 192];
        atomicAdd(&bnpart[g * 256 + 128 + 2 * tid],     a.x + b_.x + c.x + d_.x);
        atomicAdd(&bnpart[g * 256 + 128 + 2 * tid + 1], a.y + b_.y + c.y + d_.y);
    }
}

// ---------------------------------------------------------------------------
// BN finalize + att norm -> coefs[384]. 1024 threads, 8 graph-slices.
// ---------------------------------------------------------------------------
__global__ __launch_bounds__(1024, 1) void bnfin_kernel(
    const float* __restrict__ bnpart, float n,
    const float* __restrict__ gamma, const float* __restrict__ beta,
    const float* __restrict__ att, float* __restrict__ coefs)
{
    __shared__ float ssum[8][128];
    __shared__ float ssq[8][128];
    __shared__ float r[128];
    const int t = threadIdx.x & 127, slice = threadIdx.x >> 7;
    float s = 0.f, q = 0.f;
    for (int g = slice; g < G; g += 8) {
        s += bnpart[g * 256 + t];
        q += bnpart[g * 256 + 128 + t];
    }
    ssum[slice][t] = s; ssq[slice][t] = q;
    if (threadIdx.x < 128) { float av = att[t]; r[t] = av * av; }
    __syncthreads();
    if (threadIdx.x < 128) {
        float S = 0.f, Q = 0.f;
#pragma unroll
        for (int k = 0; k < 8; ++k) { S += ssum[k][t]; Q += ssq[k][t]; }
        for (int st = 64; st > 0; st >>= 1) {
            if (t < st) r[t] += r[t + st];
            __syncthreads();
        }
        float norm = sqrtf(r[0]);
        float mu   = S / n;
        float var  = Q / n - mu * mu;
        float inv  = rsqrtf(var + 1e-5f);
        float a    = gamma[t] * inv;
        coefs[t]        = a;
        coefs[128 + t]  = beta[t] - mu * a;
        coefs[256 + t]  = att[t] / norm;
    }
}

// ---------------------------------------------------------------------------
// score: grid (G,8) x 256 thr. score_g[g*NCUR+i] = tanh(sum relu(a*x+c)*t).
// ---------------------------------------------------------------------------
template<int NCUR>
__global__ __launch_bounds__(256, 8) void score_kernel(
    const float* __restrict__ gcn, const float* __restrict__ coefs,
    float* __restrict__ score_g)
{
    constexpr int CHUNK = (NCUR + 7) / 8;
    const int g = blockIdx.x, s = blockIdx.y;
    const int tid = threadIdx.x, lane = tid & 63, w = tid >> 6;
    const int nb = g * NCUR;
    const int i0 = s * CHUNK;
    const int i1 = (i0 + CHUNK < NCUR) ? i0 + CHUNK : NCUR;

    const float a0 = coefs[lane],       a1 = coefs[64 + lane];
    const float c0 = coefs[128 + lane], c1 = coefs[192 + lane];
    const float t0 = coefs[256 + lane], t1 = coefs[320 + lane];

    for (int i = i0 + w; i < i1; i += 4) {
        const float* row = gcn + (size_t)(nb + i) * 128;
        float h0 = fmaxf(a0 * row[lane] + c0, 0.f);
        float h1 = fmaxf(a1 * row[64 + lane] + c1, 0.f);
        float p  = h0 * t0 + h1 * t1;
#pragma unroll
        for (int off = 32; off > 0; off >>= 1) p += __shfl_down(p, off);
        if (lane == 0) score_g[nb + i] = tanhf(p);
    }
}

// ---------------------------------------------------------------------------
// select: one block per graph. keys/rank from score_g -> n2o_g + cmap remap;
// if BUILD: next layer's CSR+rowptr.
// ---------------------------------------------------------------------------
template<int NCUR, int KK, bool BUILD>
__global__ __launch_bounds__(1024, 1) void select_kernel(
    const float* __restrict__ score_g, short* __restrict__ cmap,
    unsigned short* __restrict__ n2o_g,
    const int* __restrict__ src, const int* __restrict__ dst,
    unsigned short* __restrict__ csr_g, int* __restrict__ rowptr_g)
{
    __shared__ unsigned long long key_s[NCUR];
    __shared__ short o2n_s[NCUR];
    __shared__ short cmap_s[NPER];
    __shared__ int   cnt_s[512];
    __shared__ int   rowptr_s[513];
    __shared__ int   wo_s[512];
    __shared__ int   chunksum_s[9];

    const int g = blockIdx.x, tid = threadIdx.x, lane = tid & 63, w = tid >> 6;
    const int nb = g * NCUR;
    const int ebase = g * EPG, obase = g * NPER;

    for (int i = tid; i < NPER; i += 1024) cmap_s[i] = cmap[obase + i];
    for (int i = tid; i < NCUR; i += 1024) {
        unsigned u   = __float_as_uint(score_g[nb + i]);
        unsigned key = (u & 0x80000000u) ? ~u : (u | 0x80000000u);
        key_s[i] = ((unsigned long long)key << 32) |
                   (unsigned long long)(0xFFFFFFFFu - (unsigned)i);
    }
    __syncthreads();

    for (int i = tid; i < NCUR; i += 1024) {
        const unsigned long long ki = key_s[i];
        int r = 0;
#pragma unroll 8
        for (int j = 0; j < NCUR; ++j) r += (key_s[j] > ki) ? 1 : 0;
        o2n_s[i] = (r < KK) ? (short)r : (short)-1;
        if (r < KK) n2o_g[g * 512 + r] = (unsigned short)i;
    }
    __syncthreads();

    for (int o = tid; o < NPER; o += 1024) {
        int m = cmap_s[o];
        short nm = (m >= 0) ? o2n_s[m] : (short)-1;
        cmap_s[o] = nm;
        cmap[obase + o] = nm;
    }

    if (!BUILD) return;
    __syncthreads();

    if (tid < 512) cnt_s[tid] = 0;
    __syncthreads();
    for (int e = tid; e < EPG; e += 1024) {
        int sl = cmap_s[src[ebase + e] - obase];
        int dl = cmap_s[dst[ebase + e] - obase];
        if ((sl | dl) >= 0) atomicAdd(&cnt_s[dl], 1);
    }
    __syncthreads();
    int v = 0, x = 0;
    if (tid < 512) {
        v = cnt_s[tid]; x = v;
#pragma unroll
        for (int d = 1; d < 64; d <<= 1) {
            int y = __shfl_up(x, d);
            if (lane >= d) x += y;
        }
        if (lane == 63) chunksum_s[w] = x;
    }
    __syncthreads();
    if (tid == 0) {
        int acc = 0;
#pragma unroll
        for (int k = 0; k < 8; ++k) { int t = chunksum_s[k]; chunksum_s[k] = acc; acc += t; }
    }
    __syncthreads();
    if (tid < 512) {
        int excl = x - v + chunksum_s[w];
        rowptr_s[tid] = excl; wo_s[tid] = excl;
        if (tid == 511) rowptr_s[512] = excl + v;
    }
    __syncthreads();
    for (int i = tid; i <= 512; i += 1024) rowptr_g[g * 513 + i] = rowptr_s[i];
    for (int e = tid; e < EPG; e += 1024) {
        int sl = cmap_s[src[ebase + e] - obase];
        int dl = cmap_s[dst[ebase + e] - obase];
        if ((sl | dl) >= 0) {
            int pos = atomicAdd(&wo_s[dl], 1);
            csr_g[g * EPG + pos] = (unsigned short)sl;
        }
    }
}

// ---------------------------------------------------------------------------
// gate: grid (G,8) x 256 thr. Gates kept rows -> newx (if STORE), readout
// partials -> encoded atomicMax rmax + atomicAdd rsum (per-layer buffers).
// ---------------------------------------------------------------------------
template<int NCUR, int KK, bool STORE>
__global__ __launch_bounds__(256, 8) void gate_kernel(
    const float* __restrict__ gcn, const float* __restrict__ coefs,
    const float* __restrict__ score_g, const unsigned short* __restrict__ n2o_g,
    float* __restrict__ newx, unsigned* __restrict__ rmax,
    float* __restrict__ rsum)
{
    constexpr int CHUNK = (KK + 7) / 8;
    __shared__ float2 red2[256];
    const int g = blockIdx.x, s = blockIdx.y;
    const int tid = threadIdx.x, lane = tid & 63, w = tid >> 6;
    const int nb = g * NCUR;
    const int j0 = s * CHUNK;
    const int j1 = (j0 + CHUNK < KK) ? j0 + CHUNK : KK;

    const float a0 = coefs[lane],       a1 = coefs[64 + lane];
    const float c0 = coefs[128 + lane], c1 = coefs[192 + lane];

    float mx0 = -1e30f, mx1 = -1e30f, sm0 = 0.f, sm1 = 0.f;
    for (int j2 = j0 + w; j2 < j1; j2 += 4) {
        int old = n2o_g[g * 512 + j2];
        float sc = score_g[nb + old];
        const float* row = gcn + (size_t)(nb + old) * 128;
        float h0 = fmaxf(a0 * row[lane] + c0, 0.f) * sc;
        float h1 = fmaxf(a1 * row[64 + lane] + c1, 0.f) * sc;
        if (STORE) {
            float* orow = newx + (size_t)(g * KK + j2) * 128;
            orow[lane]      = h0;
            orow[64 + lane] = h1;
        }
        mx0 = fmaxf(mx0, h0); mx1 = fmaxf(mx1, h1);
        sm0 += h0; sm1 += h1;
    }
    red2[tid] = make_float2(mx0, mx1);
    __syncthreads();
    if (tid < 64) {
        float m0 = fmaxf(fmaxf(red2[tid].x, red2[tid + 64].x),
                         fmaxf(red2[tid + 128].x, red2[tid + 192].x));
        float m1 = fmaxf(fmaxf(red2[tid].y, red2[tid + 64].y),
                         fmaxf(red2[tid + 128].y, red2[tid + 192].y));
        atomicMax(&rmax[g * 128 + tid],      encf(m0));
        atomicMax(&rmax[g * 128 + 64 + tid], encf(m1));
    }
    __syncthreads();
    red2[tid] = make_float2(sm0, sm1);
    __syncthreads();
    if (tid < 64) {
        float s0 = red2[tid].x + red2[tid + 64].x + red2[tid + 128].x + red2[tid + 192].x;
        float s1 = red2[tid].y + red2[tid + 64].y + red2[tid + 128].y + red2[tid + 192].y;
        atomicAdd(&rsum[g * 128 + tid],      s0);
        atomicAdd(&rsum[g * 128 + 64 + tid], s1);
    }
}

// ---------------------------------------------------------------------------
// final MLP: combine 3 layers' readouts (decode max, mean=sum/K), then MLP.
// ---------------------------------------------------------------------------
__global__ void final_kernel(const unsigned* __restrict__ rmax,
                             const float* __restrict__ rsum,
                             const float* __restrict__ Wl1,
                             const float* __restrict__ bl1,
                             const float* __restrict__ Wl2,
                             const float* __restrict__ bl2,
                             float* __restrict__ out)
{
    __shared__ float s_s[256];
    __shared__ float hid_s[128];
    int g = blockIdx.x, t = threadIdx.x;
    s_s[t] = decf(rmax[g * 128 + t]) +
             decf(rmax[G * 128 + g * 128 + t]) +
             decf(rmax[2 * G * 128 + g * 128 + t]);
    s_s[128 + t] = rsum[g * 128 + t] * (1.0f / KP1) +
                   rsum[G * 128 + g * 128 + t] * (1.0f / KP2) +
                   rsum[2 * G * 128 + g * 128 + t] * (1.0f / KP3);
    __syncthreads();
    float acc = bl1[t];
    for (int i = 0; i < 256; ++i) acc += s_s[i] * Wl1[i * 128 + t];
    hid_s[t] = fmaxf(acc, 0.f);
    __syncthreads();
    if (t < 2) {
        float o = bl2[t];
        for (int j = 0; j < 128; ++j) o += hid_s[j] * Wl2[j * 2 + t];
        out[g * 2 + t] = o;
    }
}

// ---------------------------------------------------------------------------
extern "C" void kernel_launch(void* const* d_in, const int* in_sizes, int n_in,
                              void* d_out, int out_size, void* d_ws, size_t ws_size,
                              hipStream_t stream)
{
    const float* x    = (const float*)d_in[0];
    const int*   ei   = (const int*)d_in[1];
    const float* Wp   = (const float*)d_in[3];
    const float* bp   = (const float*)d_in[4];
    const float* W1   = (const float*)d_in[5];
    const float* b1   = (const float*)d_in[6];
    const float* g1   = (const float*)d_in[7];
    const float* be1  = (const float*)d_in[8];
    const float* att1 = (const float*)d_in[9];
    const float* W2   = (const float*)d_in[10];
    const float* b2   = (const float*)d_in[11];
    const float* g2   = (const float*)d_in[12];
    const float* be2  = (const float*)d_in[13];
    const float* att2 = (const float*)d_in[14];
    const float* W3   = (const float*)d_in[15];
    const float* b3   = (const float*)d_in[16];
    const float* g3   = (const float*)d_in[17];
    const float* be3  = (const float*)d_in[18];
    const float* att3 = (const float*)d_in[19];
    const float* Wl1  = (const float*)d_in[20];
    const float* bl1  = (const float*)d_in[21];
    const float* Wl2  = (const float*)d_in[22];
    const float* bl2  = (const float*)d_in[23];
    float* out = (float*)d_out;

    const int* srcp = ei;
    const int* dstp = ei + E_TOT;

    char* ws = (char*)d_ws;
    float*          bufA    = (float*)ws;                       // 33,554,432 B
    float*          bufB    = (float*)(ws + 33554432);          // 33,554,432 B
    unsigned short* csr     = (unsigned short*)(ws + 67108864); //  2,097,152 B
    int*            rowptr  = (int*)  (ws + 69206016);          //    262,656 B
    float*          bnpart  = (float*)(ws + 69468672);          //    393,216 B
    short*          cmap    = (short*)(ws + 69861888);          //    131,072 B
    float*          score_g = (float*)(ws + 69992960);          //    262,144 B
    unsigned short* n2o     = (unsigned short*)(ws + 70255104); //    131,072 B
    unsigned*       rmax    = (unsigned*)(ws + 70386176);       //    196,608 B
    float*          rsum    = (float*)(ws + 70582784);          //    196,608 B
    float*          coefs   = (float*)(ws + 70779392);          //      1,536 B

    float* bn0 = bnpart;
    float* bn1 = bnpart + G * 256;
    float* bn2 = bnpart + 2 * G * 256;
    unsigned* rmax0 = rmax,            * rmax1 = rmax + G * 128, * rmax2 = rmax + 2 * G * 128;
    float*    rsum0 = rsum;
    float*    rsum1 = rsum + G * 128;
    float*    rsum2 = rsum + 2 * G * 128;

    init_kernel<<<384, 256, 0, stream>>>(cmap, bnpart, rmax, rsum);
    csr_build0<<<G, 512, 0, stream>>>(srcp, dstp, csr, rowptr);

    gemm_pre<<<512, 256, 0, stream>>>(x, Wp, bp, bufA, NTOT);

    // ---- layer 1 ----
    gemm128<NPER><<<512, 256, 0, stream>>>(bufA, W1, rowptr, bufB);
    gather_kernel<NPER><<<dim3(G, 16), 256, 0, stream>>>(bufB, csr, rowptr, b1, bufA, bn0);
    bnfin_kernel<<<1, 1024, 0, stream>>>(bn0, (float)NTOT, g1, be1, att1, coefs);
    score_kernel<NPER><<<dim3(G, 8), 256, 0, stream>>>(bufA, coefs, score_g);
    select_kernel<NPER, KP1, true><<<G, 1024, 0, stream>>>(
        score_g, cmap, n2o, srcp, dstp, csr, rowptr);
    gate_kernel<NPER, KP1, true><<<dim3(G, 8), 256, 0, stream>>>(
        bufA, coefs, score_g, n2o, bufB, rmax0, rsum0);

    // ---- layer 2 ----
    gemm128<KP1><<<410, 256, 0, stream>>>(bufB, W2, rowptr, bufA);
    gather_kernel<KP1><<<dim3(G, 16), 256, 0, stream>>>(bufA, csr, rowptr, b2, bufB, bn1);
    bnfin_kernel<<<1, 1024, 0, stream>>>(bn1, (float)(G * KP1), g2, be2, att2, coefs);
    score_kernel<KP1><<<dim3(G, 8), 256, 0, stream>>>(bufB, coefs, score_g);
    select_kernel<KP1, KP2, true><<<G, 1024, 0, stream>>>(
        score_g, cmap, n2o, srcp, dstp, csr, rowptr);
    gate_kernel<KP1, KP2, true><<<dim3(G, 8), 256, 0, stream>>>(
        bufB, coefs, score_g, n2o, bufA, rmax1, rsum1);

    // ---- layer 3 ----
    gemm128<KP2><<<328, 256, 0, stream>>>(bufA, W3, rowptr, bufB);
    gather_kernel<KP2><<<dim3(G, 16), 256, 0, stream>>>(bufB, csr, rowptr, b3, bufA, bn2);
    bnfin_kernel<<<1, 1024, 0, stream>>>(bn2, (float)(G * KP2), g3, be3, att3, coefs);
    score_kernel<KP2><<<dim3(G, 8), 256, 0, stream>>>(bufA, coefs, score_g);
    select_kernel<KP2, KP3, false><<<G, 1024, 0, stream>>>(
        score_g, cmap, n2o, srcp, dstp, csr, rowptr);
    gate_kernel<KP2, KP3, false><<<dim3(G, 8), 256, 0, stream>>>(
        bufA, coefs, score_g, n2o, nullptr, rmax2, rsum2);

    final_kernel<<<G, 128, 0, stream>>>(rmax, rsum, Wl1, bl1, Wl2, bl2, out);
}

// Round 12
// 451.176 us; speedup vs baseline: 1.0782x; 1.0782x over previous
//
#include <hip/hip_runtime.h>
#include <math.h>

#define G     128
#define NPER  512
#define NTOT  65536
#define E_TOT 1048576
#define EPG   8192
#define INC   100
#define HID   128
#define KP1   410
#define KP2   328
#define KP3   263

// monotone float<->uint encoding for atomicMax over signed floats
__device__ __forceinline__ unsigned encf(float x) {
    unsigned u = __float_as_uint(x);
    return (u & 0x80000000u) ? ~u : (u | 0x80000000u);
}
__device__ __forceinline__ float decf(unsigned e) {
    return (e & 0x80000000u) ? __uint_as_float(e ^ 0x80000000u)
                             : __uint_as_float(~e);
}

// ---------------------------------------------------------------------------
// init: identity cmap, zero bnpart(3 layers) + rmax(enc 0 == -inf) + rsum
// ---------------------------------------------------------------------------
__global__ void init_kernel(short* __restrict__ cmap, float* __restrict__ bnpart,
                            unsigned* __restrict__ rmax, float* __restrict__ rsum) {
    int t = blockIdx.x * 256 + threadIdx.x;
    if (t < NTOT) cmap[t] = (short)(t & (NPER - 1));
    if (t < 3 * G * 256) bnpart[t] = 0.f;
    if (t < 3 * G * 128) { rmax[t] = 0u; rsum[t] = 0.f; }
}

// ---------------------------------------------------------------------------
// csr_build0: layer-1 CSR (identity mapping, all edges valid).
// ---------------------------------------------------------------------------
__global__ __launch_bounds__(512, 2) void csr_build0(
    const int* __restrict__ src, const int* __restrict__ dst,
    unsigned short* __restrict__ csr_g, int* __restrict__ rowptr_g)
{
    __shared__ int cnt_s[NPER];
    __shared__ int rowptr_s[NPER + 1];
    __shared__ int wo_s[NPER];
    __shared__ int chunksum_s[9];

    const int g = blockIdx.x, tid = threadIdx.x, lane = tid & 63, wv = tid >> 6;
    const int ebase = g * EPG, obase = g * NPER;

    cnt_s[tid] = 0;
    __syncthreads();
    for (int e = tid; e < EPG; e += 512)
        atomicAdd(&cnt_s[dst[ebase + e] - obase], 1);
    __syncthreads();

    int v = cnt_s[tid], x = v;
#pragma unroll
    for (int d = 1; d < 64; d <<= 1) {
        int y = __shfl_up(x, d);
        if (lane >= d) x += y;
    }
    if (lane == 63) chunksum_s[wv] = x;
    __syncthreads();
    if (tid == 0) {
        int acc = 0;
#pragma unroll
        for (int k = 0; k < 8; ++k) { int t = chunksum_s[k]; chunksum_s[k] = acc; acc += t; }
    }
    __syncthreads();
    int excl = x - v + chunksum_s[wv];
    rowptr_s[tid] = excl; wo_s[tid] = excl;
    if (tid == 511) rowptr_s[512] = excl + v;
    __syncthreads();

    for (int i = tid; i <= NPER; i += 512) rowptr_g[g * 513 + i] = rowptr_s[i];
    for (int e = tid; e < EPG; e += 512) {
        int sl = src[ebase + e] - obase, dl = dst[ebase + e] - obase;
        int pos = atomicAdd(&wo_s[dl], 1);
        csr_g[g * EPG + pos] = (unsigned short)sl;
    }
}

// ---------------------------------------------------------------------------
// gemm_pre: out = relu(A[M x 100] @ W[100 x 128] + b).
// ---------------------------------------------------------------------------
__global__ __launch_bounds__(256, 2) void gemm_pre(
    const float* __restrict__ A, const float* __restrict__ W,
    const float* __restrict__ bias, float* __restrict__ out, int M)
{
    constexpr int K = INC, KC = 32;
    __shared__ float Ws[KC][128];
    __shared__ float As[KC][132];
    const int tid  = threadIdx.x;
    const int row0 = blockIdx.x * 128;
    const int r0 = (tid >> 4) * 8;
    const int c0 = (tid & 15) * 8;

    float acc[8][8];
#pragma unroll
    for (int i = 0; i < 8; ++i)
#pragma unroll
        for (int j = 0; j < 8; ++j) acc[i][j] = 0.f;

    for (int k0 = 0; k0 < K; k0 += KC) {
        const int kc  = (K - k0 < KC) ? (K - k0) : KC;
        const int nf4 = kc >> 2;

        for (int i = tid; i < kc * 32; i += 256) {
            int kk = i >> 5, c4 = i & 31;
            *((float4*)&Ws[kk][0] + c4) =
                *((const float4*)(W + (size_t)(k0 + kk) * 128) + c4);
        }
        for (int i = tid; i < nf4 * 128; i += 256) {
            int row = i / nf4, f4 = i - row * nf4;
            float4 v = *(const float4*)(A + (size_t)(row0 + row) * K + k0 + f4 * 4);
            As[f4 * 4 + 0][row] = v.x;
            As[f4 * 4 + 1][row] = v.y;
            As[f4 * 4 + 2][row] = v.z;
            As[f4 * 4 + 3][row] = v.w;
        }
        __syncthreads();

#pragma unroll 4
        for (int kk = 0; kk < kc; ++kk) {
            float4 b0 = *(const float4*)&Ws[kk][c0];
            float4 b1 = *(const float4*)&Ws[kk][c0 + 4];
            float4 a0 = *(const float4*)&As[kk][r0];
            float4 a1 = *(const float4*)&As[kk][r0 + 4];
            float a[8] = {a0.x, a0.y, a0.z, a0.w, a1.x, a1.y, a1.z, a1.w};
            float b[8] = {b0.x, b0.y, b0.z, b0.w, b1.x, b1.y, b1.z, b1.w};
#pragma unroll
            for (int i = 0; i < 8; ++i)
#pragma unroll
                for (int j = 0; j < 8; ++j)
                    acc[i][j] += a[i] * b[j];
        }
        __syncthreads();
    }

#pragma unroll
    for (int i = 0; i < 8; ++i) {
        int row = row0 + r0 + i;
        float o[8];
#pragma unroll
        for (int j = 0; j < 8; ++j)
            o[j] = fmaxf(acc[i][j] + bias[c0 + j], 0.f);
        float* po = out + (size_t)row * 128 + c0;
        *(float4*)po       = make_float4(o[0], o[1], o[2], o[3]);
        *(float4*)(po + 4) = make_float4(o[4], o[5], o[6], o[7]);
    }
}

// ---------------------------------------------------------------------------
// gemm128<NCUR>: out[row] = dinv_row * (A[row] @ W), double-buffered LDS.
// ---------------------------------------------------------------------------
template<int NCUR>
__global__ __launch_bounds__(256, 2) void gemm128(
    const float* __restrict__ A, const float* __restrict__ W,
    const int* __restrict__ rowptr_g, float* __restrict__ out)
{
    constexpr int KC = 32;
    __shared__ float Ws[2][KC][128];
    __shared__ float As[2][KC][132];
    __shared__ float dinv_ls[128];
    const int tid  = threadIdx.x;
    const int row0 = blockIdx.x * 128;
    const int r0 = (tid >> 4) * 8;
    const int c0 = (tid & 15) * 8;

    if (tid < 128) {
        int row = row0 + tid;
        int gg = row / NCUR, ll = row - gg * NCUR;
        const int* rp = rowptr_g + gg * 513 + ll;
        dinv_ls[tid] = rsqrtf((float)(rp[1] - rp[0] + 1));
    }

    const float4* W4 = (const float4*)W;

#pragma unroll
    for (int j = 0; j < 4; ++j) {
        int i = tid + j * 256;
        int kk = i >> 5, c4 = i & 31;
        *((float4*)&Ws[0][kk][0] + c4) = W4[kk * 32 + c4];
    }
#pragma unroll
    for (int j = 0; j < 4; ++j) {
        int i = tid + j * 256;
        int row = i >> 3, f4 = i & 7;
        float4 v = *(const float4*)(A + (size_t)(row0 + row) * 128 + f4 * 4);
        As[0][f4 * 4 + 0][row] = v.x;
        As[0][f4 * 4 + 1][row] = v.y;
        As[0][f4 * 4 + 2][row] = v.z;
        As[0][f4 * 4 + 3][row] = v.w;
    }
    __syncthreads();

    float acc[8][8];
#pragma unroll
    for (int i = 0; i < 8; ++i)
#pragma unroll
        for (int j = 0; j < 8; ++j) acc[i][j] = 0.f;

    int p = 0;
    for (int k0 = 0; k0 < 128; k0 += KC) {
        const int kn = k0 + KC;
        const bool has = kn < 128;

        float4 wreg[4], areg[4];
        if (has) {
#pragma unroll
            for (int j = 0; j < 4; ++j) {
                int i = tid + j * 256;
                int kk = i >> 5, c4 = i & 31;
                wreg[j] = W4[(kn + kk) * 32 + c4];
            }
#pragma unroll
            for (int j = 0; j < 4; ++j) {
                int i = tid + j * 256;
                int row = i >> 3, f4 = i & 7;
                areg[j] = *(const float4*)(A + (size_t)(row0 + row) * 128 + kn + f4 * 4);
            }
        }

#pragma unroll 4
        for (int kk = 0; kk < KC; ++kk) {
            float4 b0 = *(const float4*)&Ws[p][kk][c0];
            float4 b1 = *(const float4*)&Ws[p][kk][c0 + 4];
            float4 a0 = *(const float4*)&As[p][kk][r0];
            float4 a1 = *(const float4*)&As[p][kk][r0 + 4];
            float a[8] = {a0.x, a0.y, a0.z, a0.w, a1.x, a1.y, a1.z, a1.w};
            float b[8] = {b0.x, b0.y, b0.z, b0.w, b1.x, b1.y, b1.z, b1.w};
#pragma unroll
            for (int i = 0; i < 8; ++i)
#pragma unroll
                for (int j = 0; j < 8; ++j)
                    acc[i][j] += a[i] * b[j];
        }

        if (has) {
            int q = p ^ 1;
#pragma unroll
            for (int j = 0; j < 4; ++j) {
                int i = tid + j * 256;
                int kk = i >> 5, c4 = i & 31;
                *((float4*)&Ws[q][kk][0] + c4) = wreg[j];
            }
#pragma unroll
            for (int j = 0; j < 4; ++j) {
                int i = tid + j * 256;
                int row = i >> 3, f4 = i & 7;
                float4 v = areg[j];
                As[q][f4 * 4 + 0][row] = v.x;
                As[q][f4 * 4 + 1][row] = v.y;
                As[q][f4 * 4 + 2][row] = v.z;
                As[q][f4 * 4 + 3][row] = v.w;
            }
        }
        __syncthreads();
        p ^= 1;
    }

#pragma unroll
    for (int i = 0; i < 8; ++i) {
        int row = row0 + r0 + i;
        float dv = dinv_ls[r0 + i];
        float o[8];
#pragma unroll
        for (int j = 0; j < 8; ++j) o[j] = acc[i][j] * dv;
        float* po = out + (size_t)row * 128 + c0;
        *(float4*)po       = make_float4(o[0], o[1], o[2], o[3]);
        *(float4*)(po + 4) = make_float4(o[4], o[5], o[6], o[7]);
    }
}

// ---------------------------------------------------------------------------
// gather v6: half-wave float4. grid (G,16), 256 thr = 8 half-waves.
//   Each 32-lane half owns one dst row at a time; a full row is 32 x float4.
//   One global_load_dwordx4 instruction fetches TWO source rows (1 KB).
//   Exec-mask handles trip-count divergence between halves (no predication).
//   xs is PRE-SCALED by dinv (gemm128 epilogue); inner op is pure add.
// ---------------------------------------------------------------------------
template<int NCUR>
__global__ __launch_bounds__(256, 8) void gather_kernel(
    const float* __restrict__ xs, const unsigned short* __restrict__ csr_g,
    const int* __restrict__ rowptr_g, const float* __restrict__ bvec,
    float* __restrict__ out, float* __restrict__ bnpart)
{
    constexpr int CHUNK = (NCUR + 15) / 16;
    constexpr int CSRCAP = 1536;
    __shared__ int rowptr_s[CHUNK + 1];
    __shared__ unsigned short csr_s[CSRCAP];
    __shared__ float4 red4[256];

    const int g = blockIdx.x, s = blockIdx.y;
    const int tid = threadIdx.x, l32 = tid & 31, hw = tid >> 5;
    const int nbase = g * NCUR;
    const int d0 = s * CHUNK;
    const int d1 = (d0 + CHUNK < NCUR) ? d0 + CHUNK : NCUR;
    const int len = d1 - d0;

    const int* rp = rowptr_g + g * 513 + d0;
    for (int i = tid; i <= len; i += 256) rowptr_s[i] = rp[i];
    __syncthreads();

    const int base = rowptr_s[0];
    int nume = rowptr_s[len] - base;
    if (nume > CSRCAP) nume = CSRCAP;
    const unsigned short* cg = csr_g + g * EPG + base;
    for (int i = tid; i < nume; i += 256) csr_s[i] = cg[i];
    __syncthreads();

    const float4* x4 = (const float4*)xs + (size_t)nbase * 32 + l32;
    float4* o4 = (float4*)out + (size_t)nbase * 32 + l32;
    const float4 b4 = ((const float4*)bvec)[l32];
    float4 sum = make_float4(0.f, 0.f, 0.f, 0.f);
    float4 sq  = make_float4(0.f, 0.f, 0.f, 0.f);

    for (int d = d0 + hw; d < d1; d += 8) {
        const int r = d - d0;
        const int ia = rowptr_s[r] - base;
        const int n  = rowptr_s[r + 1] - rowptr_s[r];
        const float dv = rsqrtf((float)(n + 1));

        float4 acc0 = x4[(size_t)d * 32];          // self term (pre-scaled)
        float4 acc1 = make_float4(0.f, 0.f, 0.f, 0.f);
        int t = 0;
#pragma unroll 2
        for (; t + 1 < n; t += 2) {
            int s0 = csr_s[ia + t], s1 = csr_s[ia + t + 1];
            float4 v0 = x4[(size_t)s0 * 32];
            float4 v1 = x4[(size_t)s1 * 32];
            acc0.x += v0.x; acc0.y += v0.y; acc0.z += v0.z; acc0.w += v0.w;
            acc1.x += v1.x; acc1.y += v1.y; acc1.z += v1.z; acc1.w += v1.w;
        }
        if (t < n) {
            float4 v0 = x4[(size_t)csr_s[ia + t] * 32];
            acc0.x += v0.x; acc0.y += v0.y; acc0.z += v0.z; acc0.w += v0.w;
        }
        float4 o;
        o.x = b4.x + dv * (acc0.x + acc1.x);
        o.y = b4.y + dv * (acc0.y + acc1.y);
        o.z = b4.z + dv * (acc0.z + acc1.z);
        o.w = b4.w + dv * (acc0.w + acc1.w);
        o4[(size_t)d * 32] = o;
        sum.x += o.x; sum.y += o.y; sum.z += o.z; sum.w += o.w;
        sq.x += o.x * o.x; sq.y += o.y * o.y;
        sq.z += o.z * o.z; sq.w += o.w * o.w;
    }

    // BN partials: channel ch = l32*4 + comp; redf[h*128 + ch] is contiguous
    const float* redf = (const float*)red4;
    red4[tid] = sum; __syncthreads();
    if (tid < 128) {
        float v = 0.f;
#pragma unroll
        for (int h = 0; h < 8; ++h) v += redf[h * 128 + tid];
        atomicAdd(&bnpart[g * 256 + tid], v);
    }
    __syncthreads();
    red4[tid] = sq; __syncthreads();
    if (tid < 128) {
        float v = 0.f;
#pragma unroll
        for (int h = 0; h < 8; ++h) v += redf[h * 128 + tid];
        atomicAdd(&bnpart[g * 256 + 128 + tid], v);
    }
}

// ---------------------------------------------------------------------------
// BN finalize + att norm -> coefs[384]. 1024 threads, 8 graph-slices.
// ---------------------------------------------------------------------------
__global__ __launch_bounds__(1024, 1) void bnfin_kernel(
    const float* __restrict__ bnpart, float n,
    const float* __restrict__ gamma, const float* __restrict__ beta,
    const float* __restrict__ att, float* __restrict__ coefs)
{
    __shared__ float ssum[8][128];
    __shared__ float ssq[8][128];
    __shared__ float r[128];
    const int t = threadIdx.x & 127, slice = threadIdx.x >> 7;
    float s = 0.f, q = 0.f;
    for (int g = slice; g < G; g += 8) {
        s += bnpart[g * 256 + t];
        q += bnpart[g * 256 + 128 + t];
    }
    ssum[slice][t] = s; ssq[slice][t] = q;
    if (threadIdx.x < 128) { float av = att[t]; r[t] = av * av; }
    __syncthreads();
    if (threadIdx.x < 128) {
        float S = 0.f, Q = 0.f;
#pragma unroll
        for (int k = 0; k < 8; ++k) { S += ssum[k][t]; Q += ssq[k][t]; }
        for (int st = 64; st > 0; st >>= 1) {
            if (t < st) r[t] += r[t + st];
            __syncthreads();
        }
        float norm = sqrtf(r[0]);
        float mu   = S / n;
        float var  = Q / n - mu * mu;
        float inv  = rsqrtf(var + 1e-5f);
        float a    = gamma[t] * inv;
        coefs[t]        = a;
        coefs[128 + t]  = beta[t] - mu * a;
        coefs[256 + t]  = att[t] / norm;
    }
}

// ---------------------------------------------------------------------------
// score: grid (G,8) x 256 thr. score_g[g*NCUR+i] = tanh(sum relu(a*x+c)*t).
// ---------------------------------------------------------------------------
template<int NCUR>
__global__ __launch_bounds__(256, 8) void score_kernel(
    const float* __restrict__ gcn, const float* __restrict__ coefs,
    float* __restrict__ score_g)
{
    constexpr int CHUNK = (NCUR + 7) / 8;
    const int g = blockIdx.x, s = blockIdx.y;
    const int tid = threadIdx.x, lane = tid & 63, w = tid >> 6;
    const int nb = g * NCUR;
    const int i0 = s * CHUNK;
    const int i1 = (i0 + CHUNK < NCUR) ? i0 + CHUNK : NCUR;

    const float a0 = coefs[lane],       a1 = coefs[64 + lane];
    const float c0 = coefs[128 + lane], c1 = coefs[192 + lane];
    const float t0 = coefs[256 + lane], t1 = coefs[320 + lane];

    for (int i = i0 + w; i < i1; i += 4) {
        const float* row = gcn + (size_t)(nb + i) * 128;
        float h0 = fmaxf(a0 * row[lane] + c0, 0.f);
        float h1 = fmaxf(a1 * row[64 + lane] + c1, 0.f);
        float p  = h0 * t0 + h1 * t1;
#pragma unroll
        for (int off = 32; off > 0; off >>= 1) p += __shfl_down(p, off);
        if (lane == 0) score_g[nb + i] = tanhf(p);
    }
}

// ---------------------------------------------------------------------------
// select: one block per graph. keys/rank from score_g -> n2o_g + cmap remap;
// if BUILD: next layer's CSR+rowptr.
// ---------------------------------------------------------------------------
template<int NCUR, int KK, bool BUILD>
__global__ __launch_bounds__(1024, 1) void select_kernel(
    const float* __restrict__ score_g, short* __restrict__ cmap,
    unsigned short* __restrict__ n2o_g,
    const int* __restrict__ src, const int* __restrict__ dst,
    unsigned short* __restrict__ csr_g, int* __restrict__ rowptr_g)
{
    __shared__ unsigned long long key_s[NCUR];
    __shared__ short o2n_s[NCUR];
    __shared__ short cmap_s[NPER];
    __shared__ int   cnt_s[512];
    __shared__ int   rowptr_s[513];
    __shared__ int   wo_s[512];
    __shared__ int   chunksum_s[9];

    const int g = blockIdx.x, tid = threadIdx.x, lane = tid & 63, w = tid >> 6;
    const int nb = g * NCUR;
    const int ebase = g * EPG, obase = g * NPER;

    for (int i = tid; i < NPER; i += 1024) cmap_s[i] = cmap[obase + i];
    for (int i = tid; i < NCUR; i += 1024) {
        unsigned u   = __float_as_uint(score_g[nb + i]);
        unsigned key = (u & 0x80000000u) ? ~u : (u | 0x80000000u);
        key_s[i] = ((unsigned long long)key << 32) |
                   (unsigned long long)(0xFFFFFFFFu - (unsigned)i);
    }
    __syncthreads();

    for (int i = tid; i < NCUR; i += 1024) {
        const unsigned long long ki = key_s[i];
        int r = 0;
#pragma unroll 8
        for (int j = 0; j < NCUR; ++j) r += (key_s[j] > ki) ? 1 : 0;
        o2n_s[i] = (r < KK) ? (short)r : (short)-1;
        if (r < KK) n2o_g[g * 512 + r] = (unsigned short)i;
    }
    __syncthreads();

    for (int o = tid; o < NPER; o += 1024) {
        int m = cmap_s[o];
        short nm = (m >= 0) ? o2n_s[m] : (short)-1;
        cmap_s[o] = nm;
        cmap[obase + o] = nm;
    }

    if (!BUILD) return;
    __syncthreads();

    if (tid < 512) cnt_s[tid] = 0;
    __syncthreads();
    for (int e = tid; e < EPG; e += 1024) {
        int sl = cmap_s[src[ebase + e] - obase];
        int dl = cmap_s[dst[ebase + e] - obase];
        if ((sl | dl) >= 0) atomicAdd(&cnt_s[dl], 1);
    }
    __syncthreads();
    int v = 0, x = 0;
    if (tid < 512) {
        v = cnt_s[tid]; x = v;
#pragma unroll
        for (int d = 1; d < 64; d <<= 1) {
            int y = __shfl_up(x, d);
            if (lane >= d) x += y;
        }
        if (lane == 63) chunksum_s[w] = x;
    }
    __syncthreads();
    if (tid == 0) {
        int acc = 0;
#pragma unroll
        for (int k = 0; k < 8; ++k) { int t = chunksum_s[k]; chunksum_s[k] = acc; acc += t; }
    }
    __syncthreads();
    if (tid < 512) {
        int excl = x - v + chunksum_s[w];
        rowptr_s[tid] = excl; wo_s[tid] = excl;
        if (tid == 511) rowptr_s[512] = excl + v;
    }
    __syncthreads();
    for (int i = tid; i <= 512; i += 1024) rowptr_g[g * 513 + i] = rowptr_s[i];
    for (int e = tid; e < EPG; e += 1024) {
        int sl = cmap_s[src[ebase + e] - obase];
        int dl = cmap_s[dst[ebase + e] - obase];
        if ((sl | dl) >= 0) {
            int pos = atomicAdd(&wo_s[dl], 1);
            csr_g[g * EPG + pos] = (unsigned short)sl;
        }
    }
}

// ---------------------------------------------------------------------------
// gate: grid (G,8) x 256 thr. Gates kept rows -> newx (if STORE), readout
// partials -> encoded atomicMax rmax + atomicAdd rsum (per-layer buffers).
// ---------------------------------------------------------------------------
template<int NCUR, int KK, bool STORE>
__global__ __launch_bounds__(256, 8) void gate_kernel(
    const float* __restrict__ gcn, const float* __restrict__ coefs,
    const float* __restrict__ score_g, const unsigned short* __restrict__ n2o_g,
    float* __restrict__ newx, unsigned* __restrict__ rmax,
    float* __restrict__ rsum)
{
    constexpr int CHUNK = (KK + 7) / 8;
    __shared__ float2 red2[256];
    const int g = blockIdx.x, s = blockIdx.y;
    const int tid = threadIdx.x, lane = tid & 63, w = tid >> 6;
    const int nb = g * NCUR;
    const int j0 = s * CHUNK;
    const int j1 = (j0 + CHUNK < KK) ? j0 + CHUNK : KK;

    const float a0 = coefs[lane],       a1 = coefs[64 + lane];
    const float c0 = coefs[128 + lane], c1 = coefs[192 + lane];

    float mx0 = -1e30f, mx1 = -1e30f, sm0 = 0.f, sm1 = 0.f;
    for (int j2 = j0 + w; j2 < j1; j2 += 4) {
        int old = n2o_g[g * 512 + j2];
        float sc = score_g[nb + old];
        const float* row = gcn + (size_t)(nb + old) * 128;
        float h0 = fmaxf(a0 * row[lane] + c0, 0.f) * sc;
        float h1 = fmaxf(a1 * row[64 + lane] + c1, 0.f) * sc;
        if (STORE) {
            float* orow = newx + (size_t)(g * KK + j2) * 128;
            orow[lane]      = h0;
            orow[64 + lane] = h1;
        }
        mx0 = fmaxf(mx0, h0); mx1 = fmaxf(mx1, h1);
        sm0 += h0; sm1 += h1;
    }
    red2[tid] = make_float2(mx0, mx1);
    __syncthreads();
    if (tid < 64) {
        float m0 = fmaxf(fmaxf(red2[tid].x, red2[tid + 64].x),
                         fmaxf(red2[tid + 128].x, red2[tid + 192].x));
        float m1 = fmaxf(fmaxf(red2[tid].y, red2[tid + 64].y),
                         fmaxf(red2[tid + 128].y, red2[tid + 192].y));
        atomicMax(&rmax[g * 128 + tid],      encf(m0));
        atomicMax(&rmax[g * 128 + 64 + tid], encf(m1));
    }
    __syncthreads();
    red2[tid] = make_float2(sm0, sm1);
    __syncthreads();
    if (tid < 64) {
        float s0 = red2[tid].x + red2[tid + 64].x + red2[tid + 128].x + red2[tid + 192].x;
        float s1 = red2[tid].y + red2[tid + 64].y + red2[tid + 128].y + red2[tid + 192].y;
        atomicAdd(&rsum[g * 128 + tid],      s0);
        atomicAdd(&rsum[g * 128 + 64 + tid], s1);
    }
}

// ---------------------------------------------------------------------------
// final MLP: combine 3 layers' readouts (decode max, mean=sum/K), then MLP.
// ---------------------------------------------------------------------------
__global__ void final_kernel(const unsigned* __restrict__ rmax,
                             const float* __restrict__ rsum,
                             const float* __restrict__ Wl1,
                             const float* __restrict__ bl1,
                             const float* __restrict__ Wl2,
                             const float* __restrict__ bl2,
                             float* __restrict__ out)
{
    __shared__ float s_s[256];
    __shared__ float hid_s[128];
    int g = blockIdx.x, t = threadIdx.x;
    s_s[t] = decf(rmax[g * 128 + t]) +
             decf(rmax[G * 128 + g * 128 + t]) +
             decf(rmax[2 * G * 128 + g * 128 + t]);
    s_s[128 + t] = rsum[g * 128 + t] * (1.0f / KP1) +
                   rsum[G * 128 + g * 128 + t] * (1.0f / KP2) +
                   rsum[2 * G * 128 + g * 128 + t] * (1.0f / KP3);
    __syncthreads();
    float acc = bl1[t];
    for (int i = 0; i < 256; ++i) acc += s_s[i] * Wl1[i * 128 + t];
    hid_s[t] = fmaxf(acc, 0.f);
    __syncthreads();
    if (t < 2) {
        float o = bl2[t];
        for (int j = 0; j < 128; ++j) o += hid_s[j] * Wl2[j * 2 + t];
        out[g * 2 + t] = o;
    }
}

// ---------------------------------------------------------------------------
extern "C" void kernel_launch(void* const* d_in, const int* in_sizes, int n_in,
                              void* d_out, int out_size, void* d_ws, size_t ws_size,
                              hipStream_t stream)
{
    const float* x    = (const float*)d_in[0];
    const int*   ei   = (const int*)d_in[1];
    const float* Wp   = (const float*)d_in[3];
    const float* bp   = (const float*)d_in[4];
    const float* W1   = (const float*)d_in[5];
    const float* b1   = (const float*)d_in[6];
    const float* g1   = (const float*)d_in[7];
    const float* be1  = (const float*)d_in[8];
    const float* att1 = (const float*)d_in[9];
    const float* W2   = (const float*)d_in[10];
    const float* b2   = (const float*)d_in[11];
    const float* g2   = (const float*)d_in[12];
    const float* be2  = (const float*)d_in[13];
    const float* att2 = (const float*)d_in[14];
    const float* W3   = (const float*)d_in[15];
    const float* b3   = (const float*)d_in[16];
    const float* g3   = (const float*)d_in[17];
    const float* be3  = (const float*)d_in[18];
    const float* att3 = (const float*)d_in[19];
    const float* Wl1  = (const float*)d_in[20];
    const float* bl1  = (const float*)d_in[21];
    const float* Wl2  = (const float*)d_in[22];
    const float* bl2  = (const float*)d_in[23];
    float* out = (float*)d_out;

    const int* srcp = ei;
    const int* dstp = ei + E_TOT;

    char* ws = (char*)d_ws;
    float*          bufA    = (float*)ws;                       // 33,554,432 B
    float*          bufB    = (float*)(ws + 33554432);          // 33,554,432 B
    unsigned short* csr     = (unsigned short*)(ws + 67108864); //  2,097,152 B
    int*            rowptr  = (int*)  (ws + 69206016);          //    262,656 B
    float*          bnpart  = (float*)(ws + 69468672);          //    393,216 B
    short*          cmap    = (short*)(ws + 69861888);          //    131,072 B
    float*          score_g = (float*)(ws + 69992960);          //    262,144 B
    unsigned short* n2o     = (unsigned short*)(ws + 70255104); //    131,072 B
    unsigned*       rmax    = (unsigned*)(ws + 70386176);       //    196,608 B
    float*          rsum    = (float*)(ws + 70582784);          //    196,608 B
    float*          coefs   = (float*)(ws + 70779392);          //      1,536 B

    float* bn0 = bnpart;
    float* bn1 = bnpart + G * 256;
    float* bn2 = bnpart + 2 * G * 256;
    unsigned* rmax0 = rmax,            * rmax1 = rmax + G * 128, * rmax2 = rmax + 2 * G * 128;
    float*    rsum0 = rsum;
    float*    rsum1 = rsum + G * 128;
    float*    rsum2 = rsum + 2 * G * 128;

    init_kernel<<<384, 256, 0, stream>>>(cmap, bnpart, rmax, rsum);
    csr_build0<<<G, 512, 0, stream>>>(srcp, dstp, csr, rowptr);

    gemm_pre<<<512, 256, 0, stream>>>(x, Wp, bp, bufA, NTOT);

    // ---- layer 1 ----
    gemm128<NPER><<<512, 256, 0, stream>>>(bufA, W1, rowptr, bufB);
    gather_kernel<NPER><<<dim3(G, 16), 256, 0, stream>>>(bufB, csr, rowptr, b1, bufA, bn0);
    bnfin_kernel<<<1, 1024, 0, stream>>>(bn0, (float)NTOT, g1, be1, att1, coefs);
    score_kernel<NPER><<<dim3(G, 8), 256, 0, stream>>>(bufA, coefs, score_g);
    select_kernel<NPER, KP1, true><<<G, 1024, 0, stream>>>(
        score_g, cmap, n2o, srcp, dstp, csr, rowptr);
    gate_kernel<NPER, KP1, true><<<dim3(G, 8), 256, 0, stream>>>(
        bufA, coefs, score_g, n2o, bufB, rmax0, rsum0);

    // ---- layer 2 ----
    gemm128<KP1><<<410, 256, 0, stream>>>(bufB, W2, rowptr, bufA);
    gather_kernel<KP1><<<dim3(G, 16), 256, 0, stream>>>(bufA, csr, rowptr, b2, bufB, bn1);
    bnfin_kernel<<<1, 1024, 0, stream>>>(bn1, (float)(G * KP1), g2, be2, att2, coefs);
    score_kernel<KP1><<<dim3(G, 8), 256, 0, stream>>>(bufB, coefs, score_g);
    select_kernel<KP1, KP2, true><<<G, 1024, 0, stream>>>(
        score_g, cmap, n2o, srcp, dstp, csr, rowptr);
    gate_kernel<KP1, KP2, true><<<dim3(G, 8), 256, 0, stream>>>(
        bufB, coefs, score_g, n2o, bufA, rmax1, rsum1);

    // ---- layer 3 ----
    gemm128<KP2><<<328, 256, 0, stream>>>(bufA, W3, rowptr, bufB);
    gather_kernel<KP2><<<dim3(G, 16), 256, 0, stream>>>(bufB, csr, rowptr, b3, bufA, bn2);
    bnfin_kernel<<<1, 1024, 0, stream>>>(bn2, (float)(G * KP2), g3, be3, att3, coefs);
    score_kernel<KP2><<<dim3(G, 8), 256, 0, stream>>>(bufA, coefs, score_g);
    select_kernel<KP2, KP3, false><<<G, 1024, 0, stream>>>(
        score_g, cmap, n2o, srcp, dstp, csr, rowptr);
    gate_kernel<KP2, KP3, false><<<dim3(G, 8), 256, 0, stream>>>(
        bufA, coefs, score_g, n2o, nullptr, rmax2, rsum2);

    final_kernel<<<G, 128, 0, stream>>>(rmax, rsum, Wl1, bl1, Wl2, bl2, out);
}